// Round 4
// baseline (382.622 us; speedup 1.0000x reference)
//
#include <hip/hip_runtime.h>
#include <stdint.h>

#define N_PTS 16384
#define EPSV 1e-5f
#define SLOPEV 0.2f

typedef __attribute__((ext_vector_type(8))) __bf16 bf16x8;
typedef __attribute__((ext_vector_type(4))) float f32x4;

union U4 { uint4 u; bf16x8 b; };

__device__ inline unsigned short f2bf(float x) {
    union { float f; uint32_t u; } v; v.f = x;
    uint32_t r = v.u + 0x7FFFu + ((v.u >> 16) & 1u);
    return (unsigned short)(r >> 16);
}
__device__ inline float bf2f(unsigned short b) {
    union { float f; uint32_t u; } v; v.u = ((uint32_t)b) << 16; return v.f;
}
// Hot-path pack: native casts -> compiler emits v_cvt_pk_bf16_f32 (RNE),
// ~1-2 ops/word vs ~7 for the manual round-and-shift (m240: scalar casts win).
__device__ inline unsigned cvt2(float lo, float hi) {
    union { __bf16 h[2]; unsigned u; } w;
    w.h[0] = (__bf16)lo; w.h[1] = (__bf16)hi;
    return w.u;
}

// ---------------- Encoder layer 1: h1 = concat(xm,xd) @ W1, + batch stats ----
__global__ __launch_bounds__(128)
void enc1_kernel(const float* __restrict__ xm, const float* __restrict__ xd,
                 const float* __restrict__ W1, float* __restrict__ h1,
                 float* __restrict__ sum1, float* __restrict__ sumsq1) {
    __shared__ __align__(16) float Ws[192 * 16];
    __shared__ float ssum[16], ssq[16];
    const int tid = threadIdx.x;
    for (int i = tid; i < 192 * 16; i += 128) Ws[i] = W1[i];
    if (tid < 16) { ssum[tid] = 0.f; ssq[tid] = 0.f; }
    __syncthreads();
    const int row = blockIdx.x * 128 + tid;
    float h[16];
#pragma unroll
    for (int c = 0; c < 16; ++c) h[c] = 0.f;
    for (int j = 0; j < 64; j += 4) {
        const float4 x = *(const float4*)(xm + (size_t)row * 64 + j);
#pragma unroll
        for (int cc = 0; cc < 4; ++cc) {
            const f32x4 w0 = *(const f32x4*)&Ws[(j + 0) * 16 + cc * 4];
            const f32x4 w1 = *(const f32x4*)&Ws[(j + 1) * 16 + cc * 4];
            const f32x4 w2 = *(const f32x4*)&Ws[(j + 2) * 16 + cc * 4];
            const f32x4 w3 = *(const f32x4*)&Ws[(j + 3) * 16 + cc * 4];
#pragma unroll
            for (int e = 0; e < 4; ++e)
                h[cc * 4 + e] += x.x * w0[e] + x.y * w1[e] + x.z * w2[e] + x.w * w3[e];
        }
    }
    for (int j = 0; j < 128; j += 4) {
        const float4 x = *(const float4*)(xd + (size_t)row * 128 + j);
#pragma unroll
        for (int cc = 0; cc < 4; ++cc) {
            const f32x4 w0 = *(const f32x4*)&Ws[(64 + j + 0) * 16 + cc * 4];
            const f32x4 w1 = *(const f32x4*)&Ws[(64 + j + 1) * 16 + cc * 4];
            const f32x4 w2 = *(const f32x4*)&Ws[(64 + j + 2) * 16 + cc * 4];
            const f32x4 w3 = *(const f32x4*)&Ws[(64 + j + 3) * 16 + cc * 4];
#pragma unroll
            for (int e = 0; e < 4; ++e)
                h[cc * 4 + e] += x.x * w0[e] + x.y * w1[e] + x.z * w2[e] + x.w * w3[e];
        }
    }
#pragma unroll
    for (int c = 0; c < 16; c += 4)
        *(float4*)(h1 + (size_t)row * 16 + c) = make_float4(h[c], h[c + 1], h[c + 2], h[c + 3]);
#pragma unroll
    for (int c = 0; c < 16; ++c) {
        atomicAdd(&ssum[c], h[c]);
        atomicAdd(&ssq[c], h[c] * h[c]);
    }
    __syncthreads();
    if (tid < 16) { atomicAdd(&sum1[tid], ssum[tid]); atomicAdd(&sumsq1[tid], ssq[tid]); }
}

// ---------------- BN finalize: scale/shift from sums ------------------------
__global__ __launch_bounds__(64)
void finalize_bn(const float* __restrict__ sum, const float* __restrict__ sumsq,
                 const float* __restrict__ g, const float* __restrict__ b,
                 float* __restrict__ scale, float* __restrict__ shift) {
    const int c = threadIdx.x;
    if (c < 16) {
        const float mean = sum[c] * (1.f / N_PTS);
        const float var = sumsq[c] * (1.f / N_PTS) - mean * mean;
        const float sc = g[c] * rsqrtf(var + EPSV);
        scale[c] = sc;
        shift[c] = b[c] - mean * sc;
    }
}

// ---------------- Encoder layer 2: BN1+lrelu -> W2, + stats -----------------
__global__ __launch_bounds__(128)
void enc2_kernel(const float* __restrict__ h1, const float* __restrict__ scale1,
                 const float* __restrict__ shift1, const float* __restrict__ W2,
                 float* __restrict__ h2, float* __restrict__ sum2, float* __restrict__ sumsq2) {
    __shared__ __align__(16) float Ws[256];
    __shared__ float ssum[16], ssq[16];
    const int tid = threadIdx.x;
    for (int i = tid; i < 256; i += 128) Ws[i] = W2[i];
    if (tid < 16) { ssum[tid] = 0.f; ssq[tid] = 0.f; }
    __syncthreads();
    const int row = blockIdx.x * 128 + tid;
    float a[16];
#pragma unroll
    for (int j = 0; j < 16; j += 4) {
        const float4 hv = *(const float4*)(h1 + (size_t)row * 16 + j);
        a[j + 0] = hv.x * scale1[j + 0] + shift1[j + 0];
        a[j + 1] = hv.y * scale1[j + 1] + shift1[j + 1];
        a[j + 2] = hv.z * scale1[j + 2] + shift1[j + 2];
        a[j + 3] = hv.w * scale1[j + 3] + shift1[j + 3];
    }
#pragma unroll
    for (int j = 0; j < 16; ++j) a[j] = a[j] >= 0.f ? a[j] : SLOPEV * a[j];
    float h[16];
#pragma unroll
    for (int c = 0; c < 16; ++c) h[c] = 0.f;
#pragma unroll
    for (int j = 0; j < 16; ++j) {
#pragma unroll
        for (int cc = 0; cc < 4; ++cc) {
            const f32x4 wv = *(const f32x4*)&Ws[j * 16 + cc * 4];
#pragma unroll
            for (int e = 0; e < 4; ++e) h[cc * 4 + e] += a[j] * wv[e];
        }
    }
#pragma unroll
    for (int c = 0; c < 16; c += 4)
        *(float4*)(h2 + (size_t)row * 16 + c) = make_float4(h[c], h[c + 1], h[c + 2], h[c + 3]);
#pragma unroll
    for (int c = 0; c < 16; ++c) {
        atomicAdd(&ssum[c], h[c]);
        atomicAdd(&ssq[c], h[c] * h[c]);
    }
    __syncthreads();
    if (tid < 16) { atomicAdd(&sum2[tid], ssum[tid]); atomicAdd(&sumsq2[tid], ssq[tid]); }
}

// ---------------- QKV: BN2+lrelu -> Q/K packed (hi/lo split), V^T bf16 ------
// Qpack row (32 bf16): [Qh*SCL | Qlo*SCL | Qh*SCL | 0], Kpack: [Kh | Kh | Klo | 0]
// so one 16x16x32 MFMA contracts QhKh + QlKh + QhKl (fp32-accurate scores).
// SCL folds softmax 1/sqrt(8) and log2(e) so p = exp2(S' - m).
__global__ __launch_bounds__(128)
void qkv_kernel(const float* __restrict__ h2, const float* __restrict__ scale2,
                const float* __restrict__ shift2, const float* __restrict__ Wq,
                const float* __restrict__ Wk, const float* __restrict__ Wv,
                unsigned short* __restrict__ Qp, unsigned short* __restrict__ Kp,
                unsigned short* __restrict__ Vt) {
    __shared__ __align__(16) float wqs[128], wks[128], wvs[1024];
    const int tid = threadIdx.x;
    for (int i = tid; i < 128; i += 128) { wqs[i] = Wq[i]; wks[i] = Wk[i]; }
    for (int i = tid; i < 1024; i += 128) wvs[i] = Wv[i];
    __syncthreads();
    const int row = blockIdx.x * 128 + tid;
    float a[16];
#pragma unroll
    for (int j = 0; j < 16; j += 4) {
        const float4 hv = *(const float4*)(h2 + (size_t)row * 16 + j);
        a[j + 0] = hv.x * scale2[j + 0] + shift2[j + 0];
        a[j + 1] = hv.y * scale2[j + 1] + shift2[j + 1];
        a[j + 2] = hv.z * scale2[j + 2] + shift2[j + 2];
        a[j + 3] = hv.w * scale2[j + 3] + shift2[j + 3];
    }
#pragma unroll
    for (int j = 0; j < 16; ++j) a[j] = a[j] >= 0.f ? a[j] : SLOPEV * a[j];

    const float SCL = (float)(1.4426950408889634 / 2.8284271247461903); // log2(e)/sqrt(8)
    union RowU { unsigned short s[32]; uint4 u[4]; } qr, kr;
#pragma unroll
    for (int o = 0; o < 8; ++o) {
        float sq = 0.f, sk = 0.f;
#pragma unroll
        for (int j = 0; j < 16; ++j) {
            sq += a[j] * wqs[j * 8 + o];
            sk += a[j] * wks[j * 8 + o];
        }
        const float qs = sq * SCL;
        const unsigned short qh = f2bf(qs);
        const unsigned short ql = f2bf(qs - bf2f(qh));
        qr.s[o] = qh; qr.s[8 + o] = ql; qr.s[16 + o] = qh; qr.s[24 + o] = 0;
        const unsigned short kh = f2bf(sk);
        const unsigned short kl = f2bf(sk - bf2f(kh));
        kr.s[o] = kh; kr.s[8 + o] = kh; kr.s[16 + o] = kl; kr.s[24 + o] = 0;
    }
#pragma unroll
    for (int k4 = 0; k4 < 4; ++k4) {
        *(uint4*)(Qp + (size_t)row * 32 + k4 * 8) = qr.u[k4];
        *(uint4*)(Kp + (size_t)row * 32 + k4 * 8) = kr.u[k4];
    }
#pragma unroll
    for (int d = 0; d < 64; ++d) {
        float sv = 0.f;
#pragma unroll
        for (int j = 0; j < 16; ++j) sv += a[j] * wvs[j * 64 + d];
        Vt[(size_t)d * N_PTS + row] = f2bf(sv); // coalesced across threads per d
    }
}

// ---------------- Flash attention with kv-split partials --------------------
// grid (nsplit, 32 q-blocks) x 512thr. nsplit=8 => split == XCD id.
// Wave w owns q rows [qblk*512 + w*64, +64) as 4 q-tiles of 16.
// S^T = mfma(A=Kpack, B=Qpack): C/D col=lane&15=q, row=4g+r=kv (HW-verified map).
// P^T repacked to B-frag (kv=8g+j per lane) via 8 shfl + selects; O^T=mfma(V^T,P^T).
__global__ __launch_bounds__(512, 2)
void attn_kernel(const unsigned short* __restrict__ Qp,
                 const unsigned short* __restrict__ Kp,
                 const unsigned short* __restrict__ Vt,
                 float* __restrict__ partO, float* __restrict__ partML,
                 int kv_per_split) {
    __shared__ __align__(16) unsigned short vlds[64 * 136]; // [64 d][128 kv], stride 136 (pad)
    const int tid = threadIdx.x;
    const int w = tid >> 6;
    const int l = tid & 63;
    const int g = l >> 4;
    const int c = l & 15;
    const int split = blockIdx.x;
    const int qbase = blockIdx.y * 512 + w * 64;
    const int kv0 = split * kv_per_split;
    const int nstage = kv_per_split >> 7;

    U4 qf[4];
#pragma unroll
    for (int qt = 0; qt < 4; ++qt)
        qf[qt].u = *(const uint4*)(Qp + (size_t)(qbase + qt * 16 + c) * 32 + g * 8);

    f32x4 acc[4][4];
#pragma unroll
    for (int qt = 0; qt < 4; ++qt)
#pragma unroll
        for (int dt = 0; dt < 4; ++dt) acc[qt][dt] = (f32x4){0.f, 0.f, 0.f, 0.f};
    float m_run[4], l_run[4];
#pragma unroll
    for (int qt = 0; qt < 4; ++qt) { m_run[qt] = -3.0e38f; l_run[qt] = 0.f; }

    for (int stage = 0; stage < nstage; ++stage) {
        const int kvs = kv0 + stage * 128;
        __syncthreads();
        for (int i = tid; i < 1024; i += 512) {
            const int r = i >> 4, ch = i & 15;
            *(uint4*)(vlds + r * 136 + ch * 8) =
                *(const uint4*)(Vt + (size_t)r * N_PTS + kvs + ch * 8);
        }
        __syncthreads();
        for (int sub = 0; sub < 4; ++sub) {
            const int kvg = kvs + sub * 32;
            U4 kf0, kf1;
            kf0.u = *(const uint4*)(Kp + (size_t)(kvg + c) * 32 + g * 8);
            kf1.u = *(const uint4*)(Kp + (size_t)(kvg + 16 + c) * 32 + g * 8);
            const f32x4 z4 = {0.f, 0.f, 0.f, 0.f};
            f32x4 s0[4], s1[4];
#pragma unroll
            for (int qt = 0; qt < 4; ++qt) {
                s0[qt] = __builtin_amdgcn_mfma_f32_16x16x32_bf16(kf0.b, qf[qt].b, z4, 0, 0, 0);
                s1[qt] = __builtin_amdgcn_mfma_f32_16x16x32_bf16(kf1.b, qf[qt].b, z4, 0, 0, 0);
            }
            float mloc[4];
            bool upd = false;
#pragma unroll
            for (int qt = 0; qt < 4; ++qt) {
                float mm = fmaxf(fmaxf(fmaxf(s0[qt][0], s0[qt][1]), fmaxf(s0[qt][2], s0[qt][3])),
                                 fmaxf(fmaxf(s1[qt][0], s1[qt][1]), fmaxf(s1[qt][2], s1[qt][3])));
                mm = fmaxf(mm, __shfl_xor(mm, 16));
                mm = fmaxf(mm, __shfl_xor(mm, 32));
                mloc[qt] = mm;
                upd = upd || (mm > m_run[qt]);
            }
            if (__any((int)upd)) { // wave-uniform rescale, usually skipped
#pragma unroll
                for (int qt = 0; qt < 4; ++qt) {
                    const float mn = fmaxf(m_run[qt], mloc[qt]);
                    const float al = __builtin_amdgcn_exp2f(m_run[qt] - mn);
                    l_run[qt] *= al;
#pragma unroll
                    for (int dt = 0; dt < 4; ++dt) acc[qt][dt] *= al;
                    m_run[qt] = mn;
                }
            }
            U4 pfb[4];
#pragma unroll
            for (int qt = 0; qt < 4; ++qt) {
                float p[8];
#pragma unroll
                for (int r = 0; r < 4; ++r) {
                    p[r] = __builtin_amdgcn_exp2f(s0[qt][r] - m_run[qt]);
                    p[4 + r] = __builtin_amdgcn_exp2f(s1[qt][r] - m_run[qt]);
                }
                float ps = ((p[0] + p[1]) + (p[2] + p[3])) + ((p[4] + p[5]) + (p[6] + p[7]));
                ps += __shfl_xor(ps, 16);
                ps += __shfl_xor(ps, 32);
                l_run[qt] += ps;
                // lane (g',c) tile0 words: w0=(kv 4g',4g'+1) w1=(kv 4g'+2,4g'+3); tile1 +16
                const unsigned t0w0 = cvt2(p[0], p[1]);
                const unsigned t0w1 = cvt2(p[2], p[3]);
                const unsigned t1w0 = cvt2(p[4], p[5]);
                const unsigned t1w1 = cvt2(p[6], p[7]);
                const int srcA = ((g & 1) << 5) + c;
                const int srcB = srcA + 16;
                const unsigned a0 = __shfl(t0w0, srcA), a1 = __shfl(t0w1, srcA);
                const unsigned a2 = __shfl(t0w0, srcB), a3 = __shfl(t0w1, srcB);
                const unsigned b0 = __shfl(t1w0, srcA), b1 = __shfl(t1w1, srcA);
                const unsigned b2 = __shfl(t1w0, srcB), b3 = __shfl(t1w1, srcB);
                const bool lo2 = (g < 2);
                pfb[qt].u = make_uint4(lo2 ? a0 : b0, lo2 ? a1 : b1,
                                       lo2 ? a2 : b2, lo2 ? a3 : b3);
            }
#pragma unroll
            for (int dt = 0; dt < 4; ++dt) {
                U4 vf;
                vf.u = *(const uint4*)(vlds + (dt * 16 + c) * 136 + sub * 32 + g * 8);
#pragma unroll
                for (int qt = 0; qt < 4; ++qt)
                    acc[qt][dt] = __builtin_amdgcn_mfma_f32_16x16x32_bf16(vf.b, pfb[qt].b,
                                                                          acc[qt][dt], 0, 0, 0);
            }
        }
    }
#pragma unroll
    for (int qt = 0; qt < 4; ++qt) {
        const int q = qbase + qt * 16 + c;
#pragma unroll
        for (int dt = 0; dt < 4; ++dt)
            *(f32x4*)(partO + ((size_t)split * N_PTS + q) * 64 + dt * 16 + g * 4) = acc[qt][dt];
        if (g == 0) {
            partML[((size_t)split * N_PTS + q) * 2 + 0] = m_run[qt];
            partML[((size_t)split * N_PTS + q) * 2 + 1] = l_run[qt];
        }
    }
}

// ---------------- Merge kv-split partials -----------------------------------
__global__ __launch_bounds__(256)
void merge_kernel(const float* __restrict__ partO, const float* __restrict__ partML,
                  float* __restrict__ out, int nsplit) {
    const int t = blockIdx.x * 256 + threadIdx.x; // 65536 = 16384 q x 4 chunks
    const int q = t >> 2, ch = t & 3;
    float M = -3.0e38f;
    for (int s = 0; s < nsplit; ++s)
        M = fmaxf(M, partML[((size_t)s * N_PTS + q) * 2 + 0]);
    float den = 0.f;
    f32x4 o0 = {0.f, 0.f, 0.f, 0.f}, o1 = o0, o2 = o0, o3 = o0;
    for (int s = 0; s < nsplit; ++s) {
        const float wgt = __builtin_amdgcn_exp2f(partML[((size_t)s * N_PTS + q) * 2 + 0] - M);
        den += wgt * partML[((size_t)s * N_PTS + q) * 2 + 1];
        const float* p = partO + ((size_t)s * N_PTS + q) * 64 + ch * 16;
        o0 += wgt * *(const f32x4*)(p + 0);
        o1 += wgt * *(const f32x4*)(p + 4);
        o2 += wgt * *(const f32x4*)(p + 8);
        o3 += wgt * *(const f32x4*)(p + 12);
    }
    const float inv = 1.f / den;
    float* po = out + (size_t)q * 64 + ch * 16;
    *(f32x4*)(po + 0) = o0 * inv;
    *(f32x4*)(po + 4) = o1 * inv;
    *(f32x4*)(po + 8) = o2 * inv;
    *(f32x4*)(po + 12) = o3 * inv;
}

extern "C" void kernel_launch(void* const* d_in, const int* in_sizes, int n_in,
                              void* d_out, int out_size, void* d_ws, size_t ws_size,
                              hipStream_t stream) {
    const float* xm = (const float*)d_in[0];
    const float* xd = (const float*)d_in[1];
    // d_in[2] = xyz (unused by reference)
    const float* W1 = (const float*)d_in[3];
    const float* g1 = (const float*)d_in[4];
    const float* b1 = (const float*)d_in[5];
    const float* W2 = (const float*)d_in[6];
    const float* g2 = (const float*)d_in[7];
    const float* b2 = (const float*)d_in[8];
    const float* Wq = (const float*)d_in[9];
    const float* Wk = (const float*)d_in[10];
    const float* Wv = (const float*)d_in[11];
    float* out = (float*)d_out;
    char* ws = (char*)d_ws;

    float* sum1 = (float*)(ws + 0);
    float* sumsq1 = (float*)(ws + 64);
    float* sum2 = (float*)(ws + 128);
    float* sumsq2 = (float*)(ws + 192);
    float* scale1 = (float*)(ws + 256);
    float* shift1 = (float*)(ws + 320);
    float* scale2 = (float*)(ws + 384);
    float* shift2 = (float*)(ws + 448);
    float* h1 = (float*)(ws + (1u << 20));
    float* h2 = (float*)(ws + (2u << 20));
    unsigned short* Qp = (unsigned short*)(ws + (3u << 20));
    unsigned short* Kp = (unsigned short*)(ws + (4u << 20));
    unsigned short* Vt = (unsigned short*)(ws + (5u << 20));
    float* partML = (float*)(ws + (7u << 20));
    float* partO = (float*)(ws + (8u << 20)); // nsplit*4MB, ends at <=40MB

    // ws_size is constant across calls, so this selection is call-invariant
    // (no graph-capture hazard). nsplit=8 wants 40MB total.
    int nsplit = 8;
    while (nsplit > 1 && (8u + 4u * (unsigned)nsplit) * (1u << 20) > ws_size) nsplit >>= 1;
    const int kv_per_split = N_PTS / nsplit;

    hipMemsetAsync(ws, 0, 256, stream); // zero stat accumulators (ws is poisoned)
    hipLaunchKernelGGL(enc1_kernel, dim3(128), dim3(128), 0, stream, xm, xd, W1, h1, sum1, sumsq1);
    hipLaunchKernelGGL(finalize_bn, dim3(1), dim3(64), 0, stream, sum1, sumsq1, g1, b1, scale1, shift1);
    hipLaunchKernelGGL(enc2_kernel, dim3(128), dim3(128), 0, stream, h1, scale1, shift1, W2, h2, sum2, sumsq2);
    hipLaunchKernelGGL(finalize_bn, dim3(1), dim3(64), 0, stream, sum2, sumsq2, g2, b2, scale2, shift2);
    hipLaunchKernelGGL(qkv_kernel, dim3(128), dim3(128), 0, stream, h2, scale2, shift2, Wq, Wk, Wv, Qp, Kp, Vt);
    hipLaunchKernelGGL(attn_kernel, dim3(nsplit, 32), dim3(512), 0, stream, Qp, Kp, Vt, partO, partML, kv_per_split);
    hipLaunchKernelGGL(merge_kernel, dim3(256), dim3(256), 0, stream, partO, partML, out, nsplit);
}

// Round 9
// 326.956 us; speedup vs baseline: 1.1703x; 1.1703x over previous
//
#include <hip/hip_runtime.h>
#include <stdint.h>

#define N_PTS 16384
#define EPSV 1e-5f
#define SLOPEV 0.2f

typedef __attribute__((ext_vector_type(8))) __bf16 bf16x8;
typedef __attribute__((ext_vector_type(4))) float f32x4;
typedef __attribute__((ext_vector_type(16))) float f32x16;

union U4 { uint4 u; bf16x8 b; };

__device__ inline unsigned short f2bf(float x) {
    union { float f; uint32_t u; } v; v.f = x;
    uint32_t r = v.u + 0x7FFFu + ((v.u >> 16) & 1u);
    return (unsigned short)(r >> 16);
}
__device__ inline float bf2f(unsigned short b) {
    union { float f; uint32_t u; } v; v.u = ((uint32_t)b) << 16; return v.f;
}
// Hot-path pack: native casts -> v_cvt_pk_bf16_f32 (RNE)
__device__ inline unsigned cvt2(float lo, float hi) {
    union { __bf16 h[2]; unsigned u; } w;
    w.h[0] = (__bf16)lo; w.h[1] = (__bf16)hi;
    return w.u;
}

// ---------------- Encoder layer 1: h1 = concat(xm,xd) @ W1, + batch stats ----
__global__ __launch_bounds__(128)
void enc1_kernel(const float* __restrict__ xm, const float* __restrict__ xd,
                 const float* __restrict__ W1, float* __restrict__ h1,
                 float* __restrict__ sum1, float* __restrict__ sumsq1) {
    __shared__ __align__(16) float Ws[192 * 16];
    __shared__ float ssum[16], ssq[16];
    const int tid = threadIdx.x;
    for (int i = tid; i < 192 * 16; i += 128) Ws[i] = W1[i];
    if (tid < 16) { ssum[tid] = 0.f; ssq[tid] = 0.f; }
    __syncthreads();
    const int row = blockIdx.x * 128 + tid;
    float h[16];
#pragma unroll
    for (int c = 0; c < 16; ++c) h[c] = 0.f;
    for (int j = 0; j < 64; j += 4) {
        const float4 x = *(const float4*)(xm + (size_t)row * 64 + j);
#pragma unroll
        for (int cc = 0; cc < 4; ++cc) {
            const f32x4 w0 = *(const f32x4*)&Ws[(j + 0) * 16 + cc * 4];
            const f32x4 w1 = *(const f32x4*)&Ws[(j + 1) * 16 + cc * 4];
            const f32x4 w2 = *(const f32x4*)&Ws[(j + 2) * 16 + cc * 4];
            const f32x4 w3 = *(const f32x4*)&Ws[(j + 3) * 16 + cc * 4];
#pragma unroll
            for (int e = 0; e < 4; ++e)
                h[cc * 4 + e] += x.x * w0[e] + x.y * w1[e] + x.z * w2[e] + x.w * w3[e];
        }
    }
    for (int j = 0; j < 128; j += 4) {
        const float4 x = *(const float4*)(xd + (size_t)row * 128 + j);
#pragma unroll
        for (int cc = 0; cc < 4; ++cc) {
            const f32x4 w0 = *(const f32x4*)&Ws[(64 + j + 0) * 16 + cc * 4];
            const f32x4 w1 = *(const f32x4*)&Ws[(64 + j + 1) * 16 + cc * 4];
            const f32x4 w2 = *(const f32x4*)&Ws[(64 + j + 2) * 16 + cc * 4];
            const f32x4 w3 = *(const f32x4*)&Ws[(64 + j + 3) * 16 + cc * 4];
#pragma unroll
            for (int e = 0; e < 4; ++e)
                h[cc * 4 + e] += x.x * w0[e] + x.y * w1[e] + x.z * w2[e] + x.w * w3[e];
        }
    }
#pragma unroll
    for (int c = 0; c < 16; c += 4)
        *(float4*)(h1 + (size_t)row * 16 + c) = make_float4(h[c], h[c + 1], h[c + 2], h[c + 3]);
#pragma unroll
    for (int c = 0; c < 16; ++c) {
        atomicAdd(&ssum[c], h[c]);
        atomicAdd(&ssq[c], h[c] * h[c]);
    }
    __syncthreads();
    if (tid < 16) { atomicAdd(&sum1[tid], ssum[tid]); atomicAdd(&sumsq1[tid], ssq[tid]); }
}

// ---------------- BN finalize: scale/shift from sums ------------------------
__global__ __launch_bounds__(64)
void finalize_bn(const float* __restrict__ sum, const float* __restrict__ sumsq,
                 const float* __restrict__ g, const float* __restrict__ b,
                 float* __restrict__ scale, float* __restrict__ shift) {
    const int c = threadIdx.x;
    if (c < 16) {
        const float mean = sum[c] * (1.f / N_PTS);
        const float var = sumsq[c] * (1.f / N_PTS) - mean * mean;
        const float sc = g[c] * rsqrtf(var + EPSV);
        scale[c] = sc;
        shift[c] = b[c] - mean * sc;
    }
}

// ---------------- Encoder layer 2: BN1+lrelu -> W2, + stats -----------------
__global__ __launch_bounds__(128)
void enc2_kernel(const float* __restrict__ h1, const float* __restrict__ scale1,
                 const float* __restrict__ shift1, const float* __restrict__ W2,
                 float* __restrict__ h2, float* __restrict__ sum2, float* __restrict__ sumsq2) {
    __shared__ __align__(16) float Ws[256];
    __shared__ float ssum[16], ssq[16];
    const int tid = threadIdx.x;
    for (int i = tid; i < 256; i += 128) Ws[i] = W2[i];
    if (tid < 16) { ssum[tid] = 0.f; ssq[tid] = 0.f; }
    __syncthreads();
    const int row = blockIdx.x * 128 + tid;
    float a[16];
#pragma unroll
    for (int j = 0; j < 16; j += 4) {
        const float4 hv = *(const float4*)(h1 + (size_t)row * 16 + j);
        a[j + 0] = hv.x * scale1[j + 0] + shift1[j + 0];
        a[j + 1] = hv.y * scale1[j + 1] + shift1[j + 1];
        a[j + 2] = hv.z * scale1[j + 2] + shift1[j + 2];
        a[j + 3] = hv.w * scale1[j + 3] + shift1[j + 3];
    }
#pragma unroll
    for (int j = 0; j < 16; ++j) a[j] = a[j] >= 0.f ? a[j] : SLOPEV * a[j];
    float h[16];
#pragma unroll
    for (int c = 0; c < 16; ++c) h[c] = 0.f;
#pragma unroll
    for (int j = 0; j < 16; ++j) {
#pragma unroll
        for (int cc = 0; cc < 4; ++cc) {
            const f32x4 wv = *(const f32x4*)&Ws[j * 16 + cc * 4];
#pragma unroll
            for (int e = 0; e < 4; ++e) h[cc * 4 + e] += a[j] * wv[e];
        }
    }
#pragma unroll
    for (int c = 0; c < 16; c += 4)
        *(float4*)(h2 + (size_t)row * 16 + c) = make_float4(h[c], h[c + 1], h[c + 2], h[c + 3]);
#pragma unroll
    for (int c = 0; c < 16; ++c) {
        atomicAdd(&ssum[c], h[c]);
        atomicAdd(&ssq[c], h[c] * h[c]);
    }
    __syncthreads();
    if (tid < 16) { atomicAdd(&sum2[tid], ssum[tid]); atomicAdd(&sumsq2[tid], ssq[tid]); }
}

// ---------------- QKV: BN2+lrelu -> Q/K packed for 32x32x16, V^T bf16 -------
// Qp row (16 bf16): [Qh*SCL(8) | Ql*SCL(8)]  (B-operand: lane group hi reads 8*hi)
// Kp row (32 bf16): [Kh(8) | Kl(8) | 0(8) | 0(8)]
//   A1 = [Kh|Kh] (both lane groups read offset 0), A2 = [Kl|0] (offset 8+8*hi)
//   => mfma1: KhQh + KhQl; mfma2: +KlQh  (fp32-exact scores, 2 MFMAs;
//   slot->k map is permutation-invariant since A and B are filled by-slot)
// SCL folds softmax 1/sqrt(8) and log2(e) so p = exp2(S' - m).
__global__ __launch_bounds__(128)
void qkv_kernel(const float* __restrict__ h2, const float* __restrict__ scale2,
                const float* __restrict__ shift2, const float* __restrict__ Wq,
                const float* __restrict__ Wk, const float* __restrict__ Wv,
                unsigned short* __restrict__ Qp, unsigned short* __restrict__ Kp,
                unsigned short* __restrict__ Vt) {
    __shared__ __align__(16) float wqs[128], wks[128], wvs[1024];
    const int tid = threadIdx.x;
    for (int i = tid; i < 128; i += 128) { wqs[i] = Wq[i]; wks[i] = Wk[i]; }
    for (int i = tid; i < 1024; i += 128) wvs[i] = Wv[i];
    __syncthreads();
    const int row = blockIdx.x * 128 + tid;
    float a[16];
#pragma unroll
    for (int j = 0; j < 16; j += 4) {
        const float4 hv = *(const float4*)(h2 + (size_t)row * 16 + j);
        a[j + 0] = hv.x * scale2[j + 0] + shift2[j + 0];
        a[j + 1] = hv.y * scale2[j + 1] + shift2[j + 1];
        a[j + 2] = hv.z * scale2[j + 2] + shift2[j + 2];
        a[j + 3] = hv.w * scale2[j + 3] + shift2[j + 3];
    }
#pragma unroll
    for (int j = 0; j < 16; ++j) a[j] = a[j] >= 0.f ? a[j] : SLOPEV * a[j];

    const float SCL = (float)(1.4426950408889634 / 2.8284271247461903); // log2(e)/sqrt(8)
    union Row16 { unsigned short s[16]; uint4 u[2]; } qr;
    union Row32 { unsigned short s[32]; uint4 u[4]; } kr;
#pragma unroll
    for (int o = 0; o < 8; ++o) {
        float sq = 0.f, sk = 0.f;
#pragma unroll
        for (int j = 0; j < 16; ++j) {
            sq += a[j] * wqs[j * 8 + o];
            sk += a[j] * wks[j * 8 + o];
        }
        const float qs = sq * SCL;
        const unsigned short qh = f2bf(qs);
        const unsigned short ql = f2bf(qs - bf2f(qh));
        qr.s[o] = qh; qr.s[8 + o] = ql;
        const unsigned short kh = f2bf(sk);
        const unsigned short kl = f2bf(sk - bf2f(kh));
        kr.s[o] = kh; kr.s[8 + o] = kl; kr.s[16 + o] = 0; kr.s[24 + o] = 0;
    }
    *(uint4*)(Qp + (size_t)row * 16 + 0) = qr.u[0];
    *(uint4*)(Qp + (size_t)row * 16 + 8) = qr.u[1];
#pragma unroll
    for (int k4 = 0; k4 < 4; ++k4)
        *(uint4*)(Kp + (size_t)row * 32 + k4 * 8) = kr.u[k4];
#pragma unroll
    for (int d = 0; d < 64; ++d) {
        float sv = 0.f;
#pragma unroll
        for (int j = 0; j < 16; ++j) sv += a[j] * wvs[j * 64 + d];
        Vt[(size_t)d * N_PTS + row] = f2bf(sv); // coalesced across threads per d
    }
}

// ---------------- Flash attention, 32x32 tiles, shuffle-free PV repack ------
// grid (nsplit, 64 q-blocks) x 512thr -> 512 blocks = 2 blocks/CU, 16 waves/CU.
// Wave w owns 32 q rows. S^T = 2x mfma_32x32x16(K*, Qpack): C/D col=lane&31=q,
// row=kv=(reg&3)+8*(reg>>2)+4*hi (HW-verified m74/m101).
// PV key idea: choose slot->kv map sigma(hi,j)=16*kvh+4*hi+(j&3)+8*(j>>2) for
// BOTH the V A-operand (LDS columns) and P B-operand. Then the B-fragment for
// kv-half kvh is exactly p[8*kvh+0..7] pairwise-packed: ZERO cross-lane ops.
// Contraction is correct for any HW slot->k map since both sides share sigma.
// vlds: [64 d][128 kv] stride 128 shorts (256B, 16B-aligned) with XOR swizzle
// byte_col ^= (row&15)<<4  -> conflict-free b64 reads, optimal b128 writes.
__global__ __launch_bounds__(512, 4)
void attn_kernel(const unsigned short* __restrict__ Qp,
                 const unsigned short* __restrict__ Kp,
                 const unsigned short* __restrict__ Vt,
                 float* __restrict__ partO, float* __restrict__ partML,
                 int kv_per_split) {
    __shared__ __align__(16) unsigned short vlds[64 * 128];
    unsigned char* vb = (unsigned char*)vlds;
    const int tid = threadIdx.x;
    const int w = tid >> 6;
    const int l = tid & 63;
    const int hi = l >> 5;
    const int c5 = l & 31;
    const int split = blockIdx.x;
    const int q = blockIdx.y * 256 + w * 32 + c5;
    const int kv0 = split * kv_per_split;
    const int nstage = kv_per_split >> 7;

    U4 qf;
    qf.u = *(const uint4*)(Qp + (size_t)q * 16 + hi * 8);

    const f32x16 Z16 = {0.f,0.f,0.f,0.f, 0.f,0.f,0.f,0.f, 0.f,0.f,0.f,0.f, 0.f,0.f,0.f,0.f};
    f32x16 acc0 = Z16, acc1 = Z16; // d 0-31, 32-63
    float m_run = -3.0e38f, l_run = 0.f;

    for (int stage = 0; stage < nstage; ++stage) {
        const int kvs = kv0 + stage * 128;
        __syncthreads();
        for (int i = tid; i < 1024; i += 512) {
            const int r = i >> 4, ch = i & 15;
            const int dst = r * 256 + ((ch * 16) ^ ((r & 15) << 4));
            *(uint4*)(vb + dst) = *(const uint4*)(Vt + (size_t)r * N_PTS + kvs + ch * 8);
        }
        __syncthreads();
#pragma unroll
        for (int sub = 0; sub < 4; ++sub) {
            const int kvg = kvs + sub * 32;
            U4 ka1, ka2;
            ka1.u = *(const uint4*)(Kp + (size_t)(kvg + c5) * 32);
            ka2.u = *(const uint4*)(Kp + (size_t)(kvg + c5) * 32 + 8 + hi * 8);
            f32x16 S = __builtin_amdgcn_mfma_f32_32x32x16_bf16(ka1.b, qf.b, Z16, 0, 0, 0);
            S = __builtin_amdgcn_mfma_f32_32x32x16_bf16(ka2.b, qf.b, S, 0, 0, 0);
            // lane (hi,q) reg i holds S[kv = kvg + (i&3)+8*(i>>2)+4*hi][q]
            float mm = fmaxf(S[0], S[1]);
#pragma unroll
            for (int i = 2; i < 16; ++i) mm = fmaxf(mm, S[i]);
            mm = fmaxf(mm, __shfl_xor(mm, 32)); // partner half (same q)
            if (__any((int)(mm > m_run + 8.f))) { // defer-max (T13, THR=8)
                const float mn = fmaxf(m_run, mm);
                const float al = __builtin_amdgcn_exp2f(m_run - mn);
                l_run *= al;
                acc0 *= al;
                acc1 *= al;
                m_run = mn;
            }
            float p[16];
#pragma unroll
            for (int i = 0; i < 16; ++i) p[i] = __builtin_amdgcn_exp2f(S[i] - m_run);
            const float ps = ((p[0] + p[1]) + (p[2] + p[3])) + ((p[4] + p[5]) + (p[6] + p[7]))
                           + ((p[8] + p[9]) + (p[10] + p[11])) + ((p[12] + p[13]) + (p[14] + p[15]));
            l_run += ps + __shfl_xor(ps, 32);
            // B-frag words for kvh: slot j <- p[8*kvh+j] (sigma map), pack pairs
            unsigned W[8];
#pragma unroll
            for (int m = 0; m < 4; ++m) {
                W[2 * m + 0] = cvt2(p[4 * m + 0], p[4 * m + 1]);
                W[2 * m + 1] = cvt2(p[4 * m + 2], p[4 * m + 3]);
            }
#pragma unroll
            for (int kvh = 0; kvh < 2; ++kvh) {
                U4 bf;
                bf.u = make_uint4(W[4 * kvh + 0], W[4 * kvh + 1],
                                  W[4 * kvh + 2], W[4 * kvh + 3]);
                // V A-operand per sigma: slots j=0..3 <- kv col 16kvh+4hi+(0..3),
                // slots 4..7 <- +8. Two 8B LDS reads per d-tile, swizzled.
                const int colb = sub * 64 + kvh * 32 + hi * 8; // byte col, bit4==0
                const int a0 = c5 * 256 + (colb ^ ((c5 & 15) << 4));
                const int r1 = 32 + c5;
                const int a1 = r1 * 256 + (colb ^ ((r1 & 15) << 4));
                const uint2 lo0 = *(const uint2*)(vb + a0);
                const uint2 hi0 = *(const uint2*)(vb + (a0 ^ 16));
                const uint2 lo1 = *(const uint2*)(vb + a1);
                const uint2 hi1 = *(const uint2*)(vb + (a1 ^ 16));
                U4 vf0, vf1;
                vf0.u = make_uint4(lo0.x, lo0.y, hi0.x, hi0.y);
                vf1.u = make_uint4(lo1.x, lo1.y, hi1.x, hi1.y);
                acc0 = __builtin_amdgcn_mfma_f32_32x32x16_bf16(vf0.b, bf.b, acc0, 0, 0, 0);
                acc1 = __builtin_amdgcn_mfma_f32_32x32x16_bf16(vf1.b, bf.b, acc1, 0, 0, 0);
            }
        }
    }
    // epilogue: O^T reg i -> d = (i&3)+8*(i>>2)+4*hi (+32 for acc1)
    const size_t obase = ((size_t)split * N_PTS + q) * 64;
#pragma unroll
    for (int m = 0; m < 4; ++m) {
        const f32x4 v0 = {acc0[4 * m + 0], acc0[4 * m + 1], acc0[4 * m + 2], acc0[4 * m + 3]};
        const f32x4 v1 = {acc1[4 * m + 0], acc1[4 * m + 1], acc1[4 * m + 2], acc1[4 * m + 3]};
        *(f32x4*)(partO + obase + 8 * m + 4 * hi) = v0;
        *(f32x4*)(partO + obase + 32 + 8 * m + 4 * hi) = v1;
    }
    if (hi == 0) {
        partML[((size_t)split * N_PTS + q) * 2 + 0] = m_run;
        partML[((size_t)split * N_PTS + q) * 2 + 1] = l_run;
    }
}

// ---------------- Merge kv-split partials -----------------------------------
__global__ __launch_bounds__(256)
void merge_kernel(const float* __restrict__ partO, const float* __restrict__ partML,
                  float* __restrict__ out, int nsplit) {
    const int t = blockIdx.x * 256 + threadIdx.x; // 65536 = 16384 q x 4 chunks
    const int q = t >> 2, ch = t & 3;
    float M = -3.0e38f;
    for (int s = 0; s < nsplit; ++s)
        M = fmaxf(M, partML[((size_t)s * N_PTS + q) * 2 + 0]);
    float den = 0.f;
    f32x4 o0 = {0.f, 0.f, 0.f, 0.f}, o1 = o0, o2 = o0, o3 = o0;
    for (int s = 0; s < nsplit; ++s) {
        const float wgt = __builtin_amdgcn_exp2f(partML[((size_t)s * N_PTS + q) * 2 + 0] - M);
        den += wgt * partML[((size_t)s * N_PTS + q) * 2 + 1];
        const float* p = partO + ((size_t)s * N_PTS + q) * 64 + ch * 16;
        o0 += wgt * *(const f32x4*)(p + 0);
        o1 += wgt * *(const f32x4*)(p + 4);
        o2 += wgt * *(const f32x4*)(p + 8);
        o3 += wgt * *(const f32x4*)(p + 12);
    }
    const float inv = 1.f / den;
    float* po = out + (size_t)q * 64 + ch * 16;
    *(f32x4*)(po + 0) = o0 * inv;
    *(f32x4*)(po + 4) = o1 * inv;
    *(f32x4*)(po + 8) = o2 * inv;
    *(f32x4*)(po + 12) = o3 * inv;
}

extern "C" void kernel_launch(void* const* d_in, const int* in_sizes, int n_in,
                              void* d_out, int out_size, void* d_ws, size_t ws_size,
                              hipStream_t stream) {
    const float* xm = (const float*)d_in[0];
    const float* xd = (const float*)d_in[1];
    // d_in[2] = xyz (unused by reference)
    const float* W1 = (const float*)d_in[3];
    const float* g1 = (const float*)d_in[4];
    const float* b1 = (const float*)d_in[5];
    const float* W2 = (const float*)d_in[6];
    const float* g2 = (const float*)d_in[7];
    const float* b2 = (const float*)d_in[8];
    const float* Wq = (const float*)d_in[9];
    const float* Wk = (const float*)d_in[10];
    const float* Wv = (const float*)d_in[11];
    float* out = (float*)d_out;
    char* ws = (char*)d_ws;

    float* sum1 = (float*)(ws + 0);
    float* sumsq1 = (float*)(ws + 64);
    float* sum2 = (float*)(ws + 128);
    float* sumsq2 = (float*)(ws + 192);
    float* scale1 = (float*)(ws + 256);
    float* shift1 = (float*)(ws + 320);
    float* scale2 = (float*)(ws + 384);
    float* shift2 = (float*)(ws + 448);
    float* h1 = (float*)(ws + (1u << 20));
    float* h2 = (float*)(ws + (2u << 20));
    unsigned short* Qp = (unsigned short*)(ws + (3u << 20));   // 512KB
    unsigned short* Kp = (unsigned short*)(ws + (4u << 20));   // 1MB
    unsigned short* Vt = (unsigned short*)(ws + (5u << 20));   // 2MB
    float* partML = (float*)(ws + (7u << 20));
    float* partO = (float*)(ws + (8u << 20)); // nsplit*4MB

    // ws_size is constant across calls -> call-invariant selection (graph-safe)
    int nsplit = 8;
    while (nsplit > 1 && (8u + 4u * (unsigned)nsplit) * (1u << 20) > ws_size) nsplit >>= 1;
    const int kv_per_split = N_PTS / nsplit;

    hipMemsetAsync(ws, 0, 256, stream); // zero stat accumulators (ws is poisoned)
    hipLaunchKernelGGL(enc1_kernel, dim3(128), dim3(128), 0, stream, xm, xd, W1, h1, sum1, sumsq1);
    hipLaunchKernelGGL(finalize_bn, dim3(1), dim3(64), 0, stream, sum1, sumsq1, g1, b1, scale1, shift1);
    hipLaunchKernelGGL(enc2_kernel, dim3(128), dim3(128), 0, stream, h1, scale1, shift1, W2, h2, sum2, sumsq2);
    hipLaunchKernelGGL(finalize_bn, dim3(1), dim3(64), 0, stream, sum2, sumsq2, g2, b2, scale2, shift2);
    hipLaunchKernelGGL(qkv_kernel, dim3(128), dim3(128), 0, stream, h2, scale2, shift2, Wq, Wk, Wv, Qp, Kp, Vt);
    hipLaunchKernelGGL(attn_kernel, dim3(nsplit, 64), dim3(512), 0, stream, Qp, Kp, Vt, partO, partML, kv_per_split);
    hipLaunchKernelGGL(merge_kernel, dim3(256), dim3(256), 0, stream, partO, partML, out, nsplit);
}

// Round 11
// 321.001 us; speedup vs baseline: 1.1920x; 1.0186x over previous
//
#include <hip/hip_runtime.h>
#include <stdint.h>

#define N_PTS 16384
#define EPSV 1e-5f
#define SLOPEV 0.2f
#define MSTATIC 16.0f  // static softmax base: scores bounded |S'|<~10 (see analysis)

typedef __attribute__((ext_vector_type(8))) __bf16 bf16x8;
typedef __attribute__((ext_vector_type(4))) float f32x4;
typedef __attribute__((ext_vector_type(16))) float f32x16;

union U4 { uint4 u; bf16x8 b; };

__device__ inline unsigned short f2bf(float x) {
    union { float f; uint32_t u; } v; v.f = x;
    uint32_t r = v.u + 0x7FFFu + ((v.u >> 16) & 1u);
    return (unsigned short)(r >> 16);
}
__device__ inline float bf2f(unsigned short b) {
    union { float f; uint32_t u; } v; v.u = ((uint32_t)b) << 16; return v.f;
}
// Hot-path pack: native casts -> v_cvt_pk_bf16_f32 (RNE)
__device__ inline unsigned cvt2(float lo, float hi) {
    union { __bf16 h[2]; unsigned u; } w;
    w.h[0] = (__bf16)lo; w.h[1] = (__bf16)hi;
    return w.u;
}

// ---------------- Encoder layer 1: h1 = concat(xm,xd) @ W1, + batch stats ----
__global__ __launch_bounds__(128)
void enc1_kernel(const float* __restrict__ xm, const float* __restrict__ xd,
                 const float* __restrict__ W1, float* __restrict__ h1,
                 float* __restrict__ sum1, float* __restrict__ sumsq1) {
    __shared__ __align__(16) float Ws[192 * 16];
    __shared__ float ssum[16], ssq[16];
    const int tid = threadIdx.x;
    for (int i = tid; i < 192 * 16; i += 128) Ws[i] = W1[i];
    if (tid < 16) { ssum[tid] = 0.f; ssq[tid] = 0.f; }
    __syncthreads();
    const int row = blockIdx.x * 128 + tid;
    float h[16];
#pragma unroll
    for (int c = 0; c < 16; ++c) h[c] = 0.f;
    for (int j = 0; j < 64; j += 4) {
        const float4 x = *(const float4*)(xm + (size_t)row * 64 + j);
#pragma unroll
        for (int cc = 0; cc < 4; ++cc) {
            const f32x4 w0 = *(const f32x4*)&Ws[(j + 0) * 16 + cc * 4];
            const f32x4 w1 = *(const f32x4*)&Ws[(j + 1) * 16 + cc * 4];
            const f32x4 w2 = *(const f32x4*)&Ws[(j + 2) * 16 + cc * 4];
            const f32x4 w3 = *(const f32x4*)&Ws[(j + 3) * 16 + cc * 4];
#pragma unroll
            for (int e = 0; e < 4; ++e)
                h[cc * 4 + e] += x.x * w0[e] + x.y * w1[e] + x.z * w2[e] + x.w * w3[e];
        }
    }
    for (int j = 0; j < 128; j += 4) {
        const float4 x = *(const float4*)(xd + (size_t)row * 128 + j);
#pragma unroll
        for (int cc = 0; cc < 4; ++cc) {
            const f32x4 w0 = *(const f32x4*)&Ws[(64 + j + 0) * 16 + cc * 4];
            const f32x4 w1 = *(const f32x4*)&Ws[(64 + j + 1) * 16 + cc * 4];
            const f32x4 w2 = *(const f32x4*)&Ws[(64 + j + 2) * 16 + cc * 4];
            const f32x4 w3 = *(const f32x4*)&Ws[(64 + j + 3) * 16 + cc * 4];
#pragma unroll
            for (int e = 0; e < 4; ++e)
                h[cc * 4 + e] += x.x * w0[e] + x.y * w1[e] + x.z * w2[e] + x.w * w3[e];
        }
    }
#pragma unroll
    for (int c = 0; c < 16; c += 4)
        *(float4*)(h1 + (size_t)row * 16 + c) = make_float4(h[c], h[c + 1], h[c + 2], h[c + 3]);
#pragma unroll
    for (int c = 0; c < 16; ++c) {
        atomicAdd(&ssum[c], h[c]);
        atomicAdd(&ssq[c], h[c] * h[c]);
    }
    __syncthreads();
    if (tid < 16) { atomicAdd(&sum1[tid], ssum[tid]); atomicAdd(&sumsq1[tid], ssq[tid]); }
}

// ---------------- BN finalize: scale/shift from sums ------------------------
__global__ __launch_bounds__(64)
void finalize_bn(const float* __restrict__ sum, const float* __restrict__ sumsq,
                 const float* __restrict__ g, const float* __restrict__ b,
                 float* __restrict__ scale, float* __restrict__ shift) {
    const int c = threadIdx.x;
    if (c < 16) {
        const float mean = sum[c] * (1.f / N_PTS);
        const float var = sumsq[c] * (1.f / N_PTS) - mean * mean;
        const float sc = g[c] * rsqrtf(var + EPSV);
        scale[c] = sc;
        shift[c] = b[c] - mean * sc;
    }
}

// ---------------- Encoder layer 2: BN1+lrelu -> W2, + stats -----------------
__global__ __launch_bounds__(128)
void enc2_kernel(const float* __restrict__ h1, const float* __restrict__ scale1,
                 const float* __restrict__ shift1, const float* __restrict__ W2,
                 float* __restrict__ h2, float* __restrict__ sum2, float* __restrict__ sumsq2) {
    __shared__ __align__(16) float Ws[256];
    __shared__ float ssum[16], ssq[16];
    const int tid = threadIdx.x;
    for (int i = tid; i < 256; i += 128) Ws[i] = W2[i];
    if (tid < 16) { ssum[tid] = 0.f; ssq[tid] = 0.f; }
    __syncthreads();
    const int row = blockIdx.x * 128 + tid;
    float a[16];
#pragma unroll
    for (int j = 0; j < 16; j += 4) {
        const float4 hv = *(const float4*)(h1 + (size_t)row * 16 + j);
        a[j + 0] = hv.x * scale1[j + 0] + shift1[j + 0];
        a[j + 1] = hv.y * scale1[j + 1] + shift1[j + 1];
        a[j + 2] = hv.z * scale1[j + 2] + shift1[j + 2];
        a[j + 3] = hv.w * scale1[j + 3] + shift1[j + 3];
    }
#pragma unroll
    for (int j = 0; j < 16; ++j) a[j] = a[j] >= 0.f ? a[j] : SLOPEV * a[j];
    float h[16];
#pragma unroll
    for (int c = 0; c < 16; ++c) h[c] = 0.f;
#pragma unroll
    for (int j = 0; j < 16; ++j) {
#pragma unroll
        for (int cc = 0; cc < 4; ++cc) {
            const f32x4 wv = *(const f32x4*)&Ws[j * 16 + cc * 4];
#pragma unroll
            for (int e = 0; e < 4; ++e) h[cc * 4 + e] += a[j] * wv[e];
        }
    }
#pragma unroll
    for (int c = 0; c < 16; c += 4)
        *(float4*)(h2 + (size_t)row * 16 + c) = make_float4(h[c], h[c + 1], h[c + 2], h[c + 3]);
#pragma unroll
    for (int c = 0; c < 16; ++c) {
        atomicAdd(&ssum[c], h[c]);
        atomicAdd(&ssq[c], h[c] * h[c]);
    }
    __syncthreads();
    if (tid < 16) { atomicAdd(&sum2[tid], ssum[tid]); atomicAdd(&sumsq2[tid], ssq[tid]); }
}

// ---------------- QKV: BN2+lrelu -> Q/K packed for 32x32x16, V^T bf16 -------
// Qp row (16 bf16): [Qh*SCL(8) | Ql*SCL(8)]  (B-operand: lane group hi reads 8*hi)
// Kp row (32 bf16): [Kh(8) | Kl(8) | 0(8) | 0(8)]
//   A1 = [Kh|Kh] (both lane groups read offset 0), A2 = [Kl|0] (offset 8+8*hi)
//   => mfma1: KhQh + KhQl; mfma2: +KlQh  (fp32-exact scores, 2 MFMAs;
//   slot->k map is permutation-invariant since A and B are filled by-slot)
// SCL folds softmax 1/sqrt(8) and log2(e) so p = exp2(S' - MSTATIC).
__global__ __launch_bounds__(128)
void qkv_kernel(const float* __restrict__ h2, const float* __restrict__ scale2,
                const float* __restrict__ shift2, const float* __restrict__ Wq,
                const float* __restrict__ Wk, const float* __restrict__ Wv,
                unsigned short* __restrict__ Qp, unsigned short* __restrict__ Kp,
                unsigned short* __restrict__ Vt) {
    __shared__ __align__(16) float wqs[128], wks[128], wvs[1024];
    const int tid = threadIdx.x;
    for (int i = tid; i < 128; i += 128) { wqs[i] = Wq[i]; wks[i] = Wk[i]; }
    for (int i = tid; i < 1024; i += 128) wvs[i] = Wv[i];
    __syncthreads();
    const int row = blockIdx.x * 128 + tid;
    float a[16];
#pragma unroll
    for (int j = 0; j < 16; j += 4) {
        const float4 hv = *(const float4*)(h2 + (size_t)row * 16 + j);
        a[j + 0] = hv.x * scale2[j + 0] + shift2[j + 0];
        a[j + 1] = hv.y * scale2[j + 1] + shift2[j + 1];
        a[j + 2] = hv.z * scale2[j + 2] + shift2[j + 2];
        a[j + 3] = hv.w * scale2[j + 3] + shift2[j + 3];
    }
#pragma unroll
    for (int j = 0; j < 16; ++j) a[j] = a[j] >= 0.f ? a[j] : SLOPEV * a[j];

    const float SCL = (float)(1.4426950408889634 / 2.8284271247461903); // log2(e)/sqrt(8)
    union Row16 { unsigned short s[16]; uint4 u[2]; } qr;
    union Row32 { unsigned short s[32]; uint4 u[4]; } kr;
#pragma unroll
    for (int o = 0; o < 8; ++o) {
        float sq = 0.f, sk = 0.f;
#pragma unroll
        for (int j = 0; j < 16; ++j) {
            sq += a[j] * wqs[j * 8 + o];
            sk += a[j] * wks[j * 8 + o];
        }
        const float qs = sq * SCL;
        const unsigned short qh = f2bf(qs);
        const unsigned short ql = f2bf(qs - bf2f(qh));
        qr.s[o] = qh; qr.s[8 + o] = ql;
        const unsigned short kh = f2bf(sk);
        const unsigned short kl = f2bf(sk - bf2f(kh));
        kr.s[o] = kh; kr.s[8 + o] = kl; kr.s[16 + o] = 0; kr.s[24 + o] = 0;
    }
    *(uint4*)(Qp + (size_t)row * 16 + 0) = qr.u[0];
    *(uint4*)(Qp + (size_t)row * 16 + 8) = qr.u[1];
#pragma unroll
    for (int k4 = 0; k4 < 4; ++k4)
        *(uint4*)(Kp + (size_t)row * 32 + k4 * 8) = kr.u[k4];
#pragma unroll
    for (int d = 0; d < 64; ++d) {
        float sv = 0.f;
#pragma unroll
        for (int j = 0; j < 16; ++j) sv += a[j] * wvs[j * 64 + d];
        Vt[(size_t)d * N_PTS + row] = f2bf(sv); // coalesced across threads per d
    }
}

// ---------------- Flash attention, 32x32 tiles, static-base softmax ---------
// grid (nsplit, 64 q-blocks) x 512thr. Wave w owns 32 q rows.
// S^T = 2x mfma_32x32x16(K*, Qpack): C/D col=lane&31=q, row=kv=(reg&3)+8*(reg>>2)+4*hi.
// Static m=MSTATIC (scores bounded; no online max / rescale / branches).
// PV sigma map: slot j <-> kv 16kvh+4hi+(j&3)+8*(j>>2) on BOTH operands -> the
// B-frag is the lane's own p[8kvh+j] (zero cross-lane); V A-frag = 2x b64 LDS.
// vlds swizzle: byte addr ^= (row&15)<<3 -> bank-pair = ch^(row&15): all 16
// pairs covered, 2 lanes each (free floor). 8B staging writes keep alignment.
__global__ __launch_bounds__(512, 4)
void attn_kernel(const unsigned short* __restrict__ Qp,
                 const unsigned short* __restrict__ Kp,
                 const unsigned short* __restrict__ Vt,
                 float* __restrict__ partO, float* __restrict__ partML,
                 int kv_per_split) {
    __shared__ __align__(16) unsigned short vlds[64 * 128];
    unsigned char* vb = (unsigned char*)vlds;
    const int tid = threadIdx.x;
    const int w = tid >> 6;
    const int l = tid & 63;
    const int hi = l >> 5;
    const int c5 = l & 31;
    const int split = blockIdx.x;
    const int q = blockIdx.y * 256 + w * 32 + c5;
    const int kv0 = split * kv_per_split;
    const int nstage = kv_per_split >> 7;

    U4 qf;
    qf.u = *(const uint4*)(Qp + (size_t)q * 16 + hi * 8);

    const f32x16 Z16 = {0.f,0.f,0.f,0.f, 0.f,0.f,0.f,0.f, 0.f,0.f,0.f,0.f, 0.f,0.f,0.f,0.f};
    f32x16 acc0 = Z16, acc1 = Z16; // d 0-31, 32-63
    float l_run = 0.f;             // local-half sum; cross-half combine at end

    for (int stage = 0; stage < nstage; ++stage) {
        const int kvs = kv0 + stage * 128;
        __syncthreads();
        for (int i = tid; i < 2048; i += 512) {
            const int r = i >> 5, ch = i & 31;
            const int dst = r * 256 + ((ch * 8) ^ ((r & 15) << 3));
            *(uint2*)(vb + dst) = *(const uint2*)(Vt + (size_t)r * N_PTS + kvs + ch * 4);
        }
        __syncthreads();
#pragma unroll
        for (int sub = 0; sub < 4; ++sub) {
            const int kvg = kvs + sub * 32;
            U4 ka1, ka2;
            ka1.u = *(const uint4*)(Kp + (size_t)(kvg + c5) * 32);
            ka2.u = *(const uint4*)(Kp + (size_t)(kvg + c5) * 32 + 8 + hi * 8);
            f32x16 S = __builtin_amdgcn_mfma_f32_32x32x16_bf16(ka1.b, qf.b, Z16, 0, 0, 0);
            S = __builtin_amdgcn_mfma_f32_32x32x16_bf16(ka2.b, qf.b, S, 0, 0, 0);
            // lane (hi,q) reg i holds S[kv = kvg + (i&3)+8*(i>>2)+4*hi][q]
            float p[16];
#pragma unroll
            for (int i = 0; i < 16; ++i) p[i] = __builtin_amdgcn_exp2f(S[i] - MSTATIC);
            l_run += ((p[0] + p[1]) + (p[2] + p[3])) + ((p[4] + p[5]) + (p[6] + p[7]))
                   + ((p[8] + p[9]) + (p[10] + p[11])) + ((p[12] + p[13]) + (p[14] + p[15]));
            // B-frag words: slot j <- p[8*kvh+j] (sigma map), pack pairs
            unsigned W[8];
#pragma unroll
            for (int m = 0; m < 4; ++m) {
                W[2 * m + 0] = cvt2(p[4 * m + 0], p[4 * m + 1]);
                W[2 * m + 1] = cvt2(p[4 * m + 2], p[4 * m + 3]);
            }
#pragma unroll
            for (int kvh = 0; kvh < 2; ++kvh) {
                U4 bf;
                bf.u = make_uint4(W[4 * kvh + 0], W[4 * kvh + 1],
                                  W[4 * kvh + 2], W[4 * kvh + 3]);
                // V A-operand per sigma: slots 0-3 <- kv 16kvh+4hi+0..3 (8B),
                // slots 4-7 <- +8 (the ^16 byte chunk). Swizzled b64 reads.
                const int colb = sub * 64 + kvh * 32 + hi * 8; // byte col, bit4==0
                const int a0 = c5 * 256 + (colb ^ ((c5 & 15) << 3));
                const int r1 = 32 + c5;
                const int a1 = r1 * 256 + (colb ^ ((r1 & 15) << 3));
                const uint2 lo0 = *(const uint2*)(vb + a0);
                const uint2 hi0 = *(const uint2*)(vb + (a0 ^ 16));
                const uint2 lo1 = *(const uint2*)(vb + a1);
                const uint2 hi1 = *(const uint2*)(vb + (a1 ^ 16));
                U4 vf0, vf1;
                vf0.u = make_uint4(lo0.x, lo0.y, hi0.x, hi0.y);
                vf1.u = make_uint4(lo1.x, lo1.y, hi1.x, hi1.y);
                acc0 = __builtin_amdgcn_mfma_f32_32x32x16_bf16(vf0.b, bf.b, acc0, 0, 0, 0);
                acc1 = __builtin_amdgcn_mfma_f32_32x32x16_bf16(vf1.b, bf.b, acc1, 0, 0, 0);
            }
        }
    }
    // cross-half l combine (both halves of same q), once per wave
    l_run += __shfl_xor(l_run, 32);
    // epilogue: O^T reg i -> d = (i&3)+8*(i>>2)+4*hi (+32 for acc1)
    const size_t obase = ((size_t)split * N_PTS + q) * 64;
#pragma unroll
    for (int m = 0; m < 4; ++m) {
        const f32x4 v0 = {acc0[4 * m + 0], acc0[4 * m + 1], acc0[4 * m + 2], acc0[4 * m + 3]};
        const f32x4 v1 = {acc1[4 * m + 0], acc1[4 * m + 1], acc1[4 * m + 2], acc1[4 * m + 3]};
        *(f32x4*)(partO + obase + 8 * m + 4 * hi) = v0;
        *(f32x4*)(partO + obase + 32 + 8 * m + 4 * hi) = v1;
    }
    if (hi == 0) {
        partML[((size_t)split * N_PTS + q) * 2 + 0] = MSTATIC;
        partML[((size_t)split * N_PTS + q) * 2 + 1] = l_run;
    }
}

// ---------------- Merge kv-split partials -----------------------------------
__global__ __launch_bounds__(256)
void merge_kernel(const float* __restrict__ partO, const float* __restrict__ partML,
                  float* __restrict__ out, int nsplit) {
    const int t = blockIdx.x * 256 + threadIdx.x; // 65536 = 16384 q x 4 chunks
    const int q = t >> 2, ch = t & 3;
    float M = -3.0e38f;
    for (int s = 0; s < nsplit; ++s)
        M = fmaxf(M, partML[((size_t)s * N_PTS + q) * 2 + 0]);
    float den = 0.f;
    f32x4 o0 = {0.f, 0.f, 0.f, 0.f}, o1 = o0, o2 = o0, o3 = o0;
    for (int s = 0; s < nsplit; ++s) {
        const float wgt = __builtin_amdgcn_exp2f(partML[((size_t)s * N_PTS + q) * 2 + 0] - M);
        den += wgt * partML[((size_t)s * N_PTS + q) * 2 + 1];
        const float* p = partO + ((size_t)s * N_PTS + q) * 64 + ch * 16;
        o0 += wgt * *(const f32x4*)(p + 0);
        o1 += wgt * *(const f32x4*)(p + 4);
        o2 += wgt * *(const f32x4*)(p + 8);
        o3 += wgt * *(const f32x4*)(p + 12);
    }
    const float inv = 1.f / den;
    float* po = out + (size_t)q * 64 + ch * 16;
    *(f32x4*)(po + 0) = o0 * inv;
    *(f32x4*)(po + 4) = o1 * inv;
    *(f32x4*)(po + 8) = o2 * inv;
    *(f32x4*)(po + 12) = o3 * inv;
}

extern "C" void kernel_launch(void* const* d_in, const int* in_sizes, int n_in,
                              void* d_out, int out_size, void* d_ws, size_t ws_size,
                              hipStream_t stream) {
    const float* xm = (const float*)d_in[0];
    const float* xd = (const float*)d_in[1];
    // d_in[2] = xyz (unused by reference)
    const float* W1 = (const float*)d_in[3];
    const float* g1 = (const float*)d_in[4];
    const float* b1 = (const float*)d_in[5];
    const float* W2 = (const float*)d_in[6];
    const float* g2 = (const float*)d_in[7];
    const float* b2 = (const float*)d_in[8];
    const float* Wq = (const float*)d_in[9];
    const float* Wk = (const float*)d_in[10];
    const float* Wv = (const float*)d_in[11];
    float* out = (float*)d_out;
    char* ws = (char*)d_ws;

    float* sum1 = (float*)(ws + 0);
    float* sumsq1 = (float*)(ws + 64);
    float* sum2 = (float*)(ws + 128);
    float* sumsq2 = (float*)(ws + 192);
    float* scale1 = (float*)(ws + 256);
    float* shift1 = (float*)(ws + 320);
    float* scale2 = (float*)(ws + 384);
    float* shift2 = (float*)(ws + 448);
    float* h1 = (float*)(ws + (1u << 20));
    float* h2 = (float*)(ws + (2u << 20));
    unsigned short* Qp = (unsigned short*)(ws + (3u << 20));   // 512KB
    unsigned short* Kp = (unsigned short*)(ws + (4u << 20));   // 1MB
    unsigned short* Vt = (unsigned short*)(ws + (5u << 20));   // 2MB
    float* partML = (float*)(ws + (7u << 20));
    float* partO = (float*)(ws + (8u << 20)); // nsplit*4MB

    // ws_size is constant across calls -> call-invariant selection (graph-safe)
    int nsplit = 8;
    while (nsplit > 1 && (8u + 4u * (unsigned)nsplit) * (1u << 20) > ws_size) nsplit >>= 1;
    const int kv_per_split = N_PTS / nsplit;

    hipMemsetAsync(ws, 0, 256, stream); // zero stat accumulators (ws is poisoned)
    hipLaunchKernelGGL(enc1_kernel, dim3(128), dim3(128), 0, stream, xm, xd, W1, h1, sum1, sumsq1);
    hipLaunchKernelGGL(finalize_bn, dim3(1), dim3(64), 0, stream, sum1, sumsq1, g1, b1, scale1, shift1);
    hipLaunchKernelGGL(enc2_kernel, dim3(128), dim3(128), 0, stream, h1, scale1, shift1, W2, h2, sum2, sumsq2);
    hipLaunchKernelGGL(finalize_bn, dim3(1), dim3(64), 0, stream, sum2, sumsq2, g2, b2, scale2, shift2);
    hipLaunchKernelGGL(qkv_kernel, dim3(128), dim3(128), 0, stream, h2, scale2, shift2, Wq, Wk, Wv, Qp, Kp, Vt);
    hipLaunchKernelGGL(attn_kernel, dim3(nsplit, 64), dim3(512), 0, stream, Qp, Kp, Vt, partO, partML, kv_per_split);
    hipLaunchKernelGGL(merge_kernel, dim3(256), dim3(256), 0, stream, partO, partML, out, nsplit);
}